// Round 11
// baseline (63.328 us; speedup 1.0000x reference)
//
#include <hip/hip_runtime.h>
#include <hip/hip_bf16.h>

#define HW 3136
#define W56 56

typedef __attribute__((ext_vector_type(8))) short short8;
typedef __attribute__((ext_vector_type(4))) float f32x4;

static __device__ __forceinline__ f32x4 mfma16(short8 a, short8 b, f32x4 c) {
    return __builtin_amdgcn_mfma_f32_16x16x32_bf16(a, b, c, 0, 0, 0);
}
static __device__ __forceinline__ float b2f(unsigned short u) {
    unsigned int x = ((unsigned int)u) << 16;
    return __builtin_bit_cast(float, x);
}
static __device__ __forceinline__ unsigned short f2b(float f) {
    __hip_bfloat16 h = __float2bfloat16(f);
    return *(unsigned short*)&h;
}

// ---------------- prep ----------------
// blocks 0..3135: transpose x -> catb bf16 cols 0..255 (hi) + xlo bf16 [4HW][256]
// blocks 3136..3647: weight conversion (Wqk split hi/lo, Wv plain bf16)
__global__ __launch_bounds__(256) void prep(const float* __restrict__ x,
                                            const float* __restrict__ Wq, const float* __restrict__ Wk,
                                            const float* __restrict__ Wv,
                                            unsigned short* __restrict__ catb,
                                            unsigned short* __restrict__ xlo,
                                            unsigned short* __restrict__ Wqk_hi,
                                            unsigned short* __restrict__ Wqk_lo,
                                            unsigned short* __restrict__ Wvb) {
    __shared__ float tile[32][33];
    int bx = blockIdx.x, tid = threadIdx.x;
    if (bx < 3136) {
        int b = bx / 784, rem = bx % 784;
        int p0 = (rem >> 3) * 32, c0 = (rem & 7) * 32;
        int tx = tid & 31, ty = tid >> 5;
#pragma unroll
        for (int i = ty; i < 32; i += 8)
            tile[i][tx] = x[((size_t)b * 256 + c0 + i) * HW + p0 + tx];
        __syncthreads();
#pragma unroll
        for (int i = ty; i < 32; i += 8) {
            float v = tile[tx][i];
            unsigned short hi = f2b(v);
            unsigned short lo = f2b(v - b2f(hi));
            size_t row = (size_t)b * HW + p0 + i;
            catb[row * 512 + c0 + tx] = hi;
            xlo[row * 256 + c0 + tx] = lo;
        }
    } else {
        int i = (bx - 3136) * 256 + tid;
        if (i < 32768) {
            float w = (i < 16384) ? Wq[i] : Wk[i - 16384];
            unsigned short hi = f2b(w);
            Wqk_hi[i] = hi;
            Wqk_lo[i] = f2b(w - b2f(hi));
        }
        if (i < 131072) Wvb[i] = f2b(Wv[i]);
    }
}

// ---------------- projqk: 64 W-rows x px(32), K=256, split-bf16, software-pipelined ----------------
// grid.x = npx/32, grid.y = 2 (y=0 -> Q rows 0..63 f32 out; y=1 -> K rows 64..127 bf16 out).
__global__ __launch_bounds__(256) void projqk(const unsigned short* __restrict__ Whi,
                                              const unsigned short* __restrict__ Wlo,
                                              const unsigned short* __restrict__ Bhi_g, int bstr,
                                              const unsigned short* __restrict__ Blo_g,
                                              float* __restrict__ Qout,
                                              unsigned short* __restrict__ Kout) {
    __shared__ short Ahi[64][72], Alo[64][72];
    __shared__ short Bhi[32][72], Blo[32][72];
    int tid = threadIdx.x, lane = tid & 63, wv = tid >> 6;
    int l15 = lane & 15, lk = (lane >> 4) * 8;
    int pxb = blockIdx.x * 32;
    int y64 = blockIdx.y * 64;
    int ar0 = tid >> 3, ac = (tid & 7) * 8;
    int br = tid >> 3, bc = (tid & 7) * 8;
    f32x4 acc[2];
    acc[0] = (f32x4){0.f, 0.f, 0.f, 0.f};
    acc[1] = (f32x4){0.f, 0.f, 0.f, 0.f};

    short8 rAh0 = *(const short8*)(Whi + (size_t)(y64 + ar0) * 256 + ac);
    short8 rAl0 = *(const short8*)(Wlo + (size_t)(y64 + ar0) * 256 + ac);
    short8 rAh1 = *(const short8*)(Whi + (size_t)(y64 + ar0 + 32) * 256 + ac);
    short8 rAl1 = *(const short8*)(Wlo + (size_t)(y64 + ar0 + 32) * 256 + ac);
    short8 rBh  = *(const short8*)(Bhi_g + (size_t)(pxb + br) * bstr + bc);
    short8 rBl  = *(const short8*)(Blo_g + (size_t)(pxb + br) * 256 + bc);

#pragma unroll
    for (int t = 0; t < 4; ++t) {
        *(short8*)&Ahi[ar0][ac] = rAh0;      *(short8*)&Alo[ar0][ac] = rAl0;
        *(short8*)&Ahi[ar0 + 32][ac] = rAh1; *(short8*)&Alo[ar0 + 32][ac] = rAl1;
        *(short8*)&Bhi[br][bc] = rBh;        *(short8*)&Blo[br][bc] = rBl;
        __syncthreads();
        if (t < 3) {
            int kn = t * 64 + 64;
            rAh0 = *(const short8*)(Whi + (size_t)(y64 + ar0) * 256 + kn + ac);
            rAl0 = *(const short8*)(Wlo + (size_t)(y64 + ar0) * 256 + kn + ac);
            rAh1 = *(const short8*)(Whi + (size_t)(y64 + ar0 + 32) * 256 + kn + ac);
            rAl1 = *(const short8*)(Wlo + (size_t)(y64 + ar0 + 32) * 256 + kn + ac);
            rBh  = *(const short8*)(Bhi_g + (size_t)(pxb + br) * bstr + kn + bc);
            rBl  = *(const short8*)(Blo_g + (size_t)(pxb + br) * 256 + kn + bc);
        }
#pragma unroll
        for (int ks = 0; ks < 2; ++ks) {
            short8 ah = *(const short8*)&Ahi[wv * 16 + l15][ks * 32 + lk];
            short8 al = *(const short8*)&Alo[wv * 16 + l15][ks * 32 + lk];
            short8 bh[2], bl[2];
#pragma unroll
            for (int j = 0; j < 2; ++j) {
                bh[j] = *(const short8*)&Bhi[j * 16 + l15][ks * 32 + lk];
                bl[j] = *(const short8*)&Blo[j * 16 + l15][ks * 32 + lk];
            }
#pragma unroll
            for (int j = 0; j < 2; ++j) {
                acc[j] = mfma16(ah, bh[j], acc[j]);
                acc[j] = mfma16(ah, bl[j], acc[j]);
                acc[j] = mfma16(al, bh[j], acc[j]);
            }
        }
        __syncthreads();
    }
    int d0 = wv * 16 + (lane >> 4) * 4;
    if (blockIdx.y == 0) {
#pragma unroll
        for (int j = 0; j < 2; ++j) {
            int px = pxb + j * 16 + l15;
            *(f32x4*)(Qout + (size_t)px * 64 + d0) = acc[j];
        }
    } else {
#pragma unroll
        for (int j = 0; j < 2; ++j) {
            int px = pxb + j * 16 + l15;
            ushort4 kb;
            kb.x = f2b(acc[j][0]); kb.y = f2b(acc[j][1]);
            kb.z = f2b(acc[j][2]); kb.w = f2b(acc[j][3]);
            *(ushort4*)(Kout + (size_t)px * 64 + d0) = kb;
        }
    }
}

// ---------------- attention: 2 adjacent pixels per wave, in-register V-union sharing ----------------
// Wave owns pixels (pg, pg+1) in one image row; their 7x7 windows union to 7x8 = 56 V rows.
// V lines per 2 pixels: 448 vs 800 (each loaded element feeds BOTH pixels' FMAs).
// Per-pixel QK logits + softmax are bit-identical to the 1-px version (separate 13-load
// transposed-coalesced gathers, separate butterflies). PV per pixel sums the same 49 terms
// in the same (dy,dx)-ascending order (half-split moves: pure eps-level regrouping).
// Barrier-free: all LDS is per-wave. Union rows with both-weights-0 clamp to row 0 (w=0 exact).
__global__ __launch_bounds__(256) void attn_kernel(const float* __restrict__ Q,
                                                   const unsigned short* __restrict__ Kb,
                                                   int selfOff, int kbOff,
                                                   const unsigned short* __restrict__ V,
                                                   unsigned short* __restrict__ outb,
                                                   unsigned short* __restrict__ outlo) {
    __shared__ float wsh[4][2][64];
    __shared__ float ls[4][2][52];
    __shared__ int njs[4][2][64];
    __shared__ int njU[4][64];
    __shared__ float wU[4][2][64];
    int tid = threadIdx.x, lane = tid & 63, wv = tid >> 6;
    int nbc = gridDim.x >> 3;  // 784/8 = 98 blocks per XCD chunk
    int lb = (blockIdx.x & 7) * nbc + (blockIdx.x >> 3);
    int pg = lb * 8 + wv * 2;          // first pixel of this wave's pair (8|56: row-aligned block)
    int b = pg / HW, pix = pg % HW;
    int py = pix / W56, px0 = pix % W56;
    int gw0 = pg, gw1 = pg + 1;

    // neighbor tables for both pixels (lane = key slot j: 0 = self-key, 1..49 = 7x7 patch)
    int v0 = 0, n0 = 0, v1 = 0, n1 = 0;
    if (lane == 0) {
        v0 = 1; v1 = 1;
    } else if (lane < 50) {
        int d = lane - 1, dy = d / 7 - 3, dx = d % 7 - 3;
        int ny = py + dy;
        if (ny >= 0 && ny < W56) {
            int nx0 = px0 + dx, nx1 = px0 + 1 + dx;
            if (nx0 >= 0 && nx0 < W56) { v0 = 1; n0 = ny * W56 + nx0; }
            if (nx1 >= 0 && nx1 < W56) { v1 = 1; n1 = ny * W56 + nx1; }
        }
    }
    njs[wv][0][lane] = n0;   // per-wave LDS, same-wave readers only
    njs[wv][1][lane] = n1;

    // ---- K gathers: 2 x 13 x ushort4 (8B/lane), coalesced-transposed over bf16 K rows ----
    int rg = lane >> 4, c = lane & 15;
    f32x4 qf0 = *(const f32x4*)(Q + (size_t)gw0 * 64 + c * 4);
    f32x4 qf1 = *(const f32x4*)(Q + (size_t)gw1 * 64 + c * 4);
    ushort4 kv0[13], kv1[13];
#pragma unroll
    for (int i = 0; i < 13; ++i) {
        int r = i * 4 + rg;
        int row0 = (i == 0 && rg == 0) ? (selfOff + gw0) : (kbOff + b * HW + njs[wv][0][r]);
        int row1 = (i == 0 && rg == 0) ? (selfOff + gw1) : (kbOff + b * HW + njs[wv][1][r]);
        kv0[i] = *(const ushort4*)(Kb + (size_t)row0 * 64 + c * 4);
        kv1[i] = *(const ushort4*)(Kb + (size_t)row1 * 64 + c * 4);
    }

    // ---- logits: per-load dot + 4-step butterfly over the 16 chunk lanes ----
    float pl0[13], pl1[13];
#pragma unroll
    for (int i = 0; i < 13; ++i) {
        pl0[i] = b2f(kv0[i].x) * qf0[0] + b2f(kv0[i].y) * qf0[1] +
                 b2f(kv0[i].z) * qf0[2] + b2f(kv0[i].w) * qf0[3];
        pl1[i] = b2f(kv1[i].x) * qf1[0] + b2f(kv1[i].y) * qf1[1] +
                 b2f(kv1[i].z) * qf1[2] + b2f(kv1[i].w) * qf1[3];
    }
#pragma unroll
    for (int off = 1; off < 16; off <<= 1)
#pragma unroll
        for (int i = 0; i < 13; ++i) {
            pl0[i] += __shfl_xor(pl0[i], off);
            pl1[i] += __shfl_xor(pl1[i], off);
        }
    float my0 = 0.f, my1 = 0.f;
#pragma unroll
    for (int i = 0; i < 13; ++i) {
        my0 = (c == i) ? pl0[i] : my0;
        my1 = (c == i) ? pl1[i] : my1;
    }
    if (c < 13) {
        ls[wv][0][c * 4 + rg] = my0;
        ls[wv][1][c * 4 + rg] = my1;
    }

    // ---- softmax x2 (zero-padded OOB: logit exactly 0, in denominator) ----
    float lg0 = (lane < 50 && v0) ? ls[wv][0][lane] : 0.f;
    float lg1 = (lane < 50 && v1) ? ls[wv][1][lane] : 0.f;
    float m0 = (lane < 50) ? lg0 : -1e30f;
    float m1 = (lane < 50) ? lg1 : -1e30f;
#pragma unroll
    for (int off = 32; off; off >>= 1) {
        m0 = fmaxf(m0, __shfl_xor(m0, off));
        m1 = fmaxf(m1, __shfl_xor(m1, off));
    }
    float e0 = (lane < 50) ? __expf(lg0 - m0) : 0.f;
    float e1 = (lane < 50) ? __expf(lg1 - m1) : 0.f;
    float s0 = e0, s1 = e1;
#pragma unroll
    for (int off = 32; off; off >>= 1) {
        s0 += __shfl_xor(s0, off);
        s1 += __shfl_xor(s1, off);
    }
    // self-key column (lane 0) dropped; invalid lanes weight 0
    wsh[wv][0][lane] = (lane >= 1 && lane < 50 && v0) ? e0 / s0 : 0.f;
    wsh[wv][1][lane] = (lane >= 1 && lane < 50 && v1) ? e1 / s1 : 0.f;

    // ---- union weight/index tables: row (dy,ux), dy in [-3,3], ux in [-3,4] ----
    if (lane < 56) {
        int dy = (lane >> 3) - 3, ux = (lane & 7) - 3;
        int ny = py + dy, nxu = px0 + ux;
        int uv = (ny >= 0 && ny < W56 && nxu >= 0 && nxu < W56);
        njU[wv][lane] = uv ? ny * W56 + nxu : 0;
        float a0 = 0.f, a1 = 0.f;
        if (ux <= 3) a0 = wsh[wv][0][1 + (dy + 3) * 7 + (ux + 3)];   // pixel0: dx = ux
        if (ux >= -2) a1 = wsh[wv][1][1 + (dy + 3) * 7 + (ux + 2)];  // pixel1: dx = ux-1
        wU[wv][0][lane] = a0;
        wU[wv][1][lane] = a1;
    }

    // ---- PV over 56 union rows: half split (h=0: rows 0..27, h=1: 28..55), 8 ch/lane ----
    int h = lane >> 5, l32 = lane & 31;
    int rb = h * 28;
    float av0[8], av1[8];
#pragma unroll
    for (int cc = 0; cc < 8; ++cc) { av0[cc] = 0.f; av1[cc] = 0.f; }
    const unsigned short* vb = V + (size_t)b * HW * 512 + l32 * 8;
#pragma unroll
    for (int g = 0; g < 4; ++g) {
        float a0[7], a1[7];
        short8 vj[7];
#pragma unroll
        for (int u = 0; u < 7; ++u) {
            int row = rb + g * 7 + u;
            a0[u] = wU[wv][0][row];
            a1[u] = wU[wv][1][row];
            vj[u] = *(const short8*)(vb + (size_t)njU[wv][row] * 512);
        }
#pragma unroll
        for (int u = 0; u < 7; ++u)
#pragma unroll
            for (int cc = 0; cc < 8; ++cc) {
                float vv = b2f((unsigned short)vj[u][cc]);
                av0[cc] += a0[u] * vv;
                av1[cc] += a1[u] * vv;
            }
    }
#pragma unroll
    for (int cc = 0; cc < 8; ++cc) {
        av0[cc] += __shfl_xor(av0[cc], 32);
        av1[cc] += __shfl_xor(av1[cc], 32);
    }

    // h==0 lanes write pixel0, h==1 lanes write pixel1 (each covers all 256 ch via l32*8)
    short8 pk, lo8;
#pragma unroll
    for (int cc = 0; cc < 8; ++cc) {
        float vvv = h ? av1[cc] : av0[cc];
        unsigned short hi = f2b(vvv);
        pk[cc] = (short)hi;
        lo8[cc] = (short)f2b(vvv - b2f(hi));
    }
    int gww = h ? gw1 : gw0;
    *(short8*)(outb + (size_t)gww * 512 + l32 * 8) = pk;
    if (outlo) *(short8*)(outlo + (size_t)gww * 256 + l32 * 8) = lo8;
}

// ---------------- conv (512->256) via MFMA + BN + ReLU, software-pipelined ----------------
__global__ __launch_bounds__(256) void conv_mfma(const unsigned short* __restrict__ catb,
                                                 const unsigned short* __restrict__ Wvb,
                                                 const float* __restrict__ bv, const float* __restrict__ gamma,
                                                 const float* __restrict__ beta, const float* __restrict__ rmean,
                                                 const float* __restrict__ rvar, float* __restrict__ out) {
    __shared__ short Ald[64][72];
    __shared__ short Bld[64][72];
    int tid = threadIdx.x, lane = tid & 63, wv = tid >> 6;
    int wm = wv >> 1, wn = wv & 1;
    int l15 = lane & 15, lk = (lane >> 4) * 8;
    int n0g = blockIdx.x * 64;
    int m0g = blockIdx.y * 64;
    f32x4 acc[2][2];
#pragma unroll
    for (int i = 0; i < 2; ++i)
#pragma unroll
        for (int j = 0; j < 2; ++j) acc[i][j] = (f32x4){0.f, 0.f, 0.f, 0.f};

    float sc_[2][4], sh_[2][4];
#pragma unroll
    for (int i = 0; i < 2; ++i) {
        int ob = m0g + wm * 32 + i * 16 + (lane >> 4) * 4;
#pragma unroll
        for (int r = 0; r < 4; ++r) {
            int o = ob + r;
            float s = gamma[o] * rsqrtf(rvar[o] + 1e-5f);
            sc_[i][r] = s;
            sh_[i][r] = (bv[o] - rmean[o]) * s + beta[o];
        }
    }

    int r0 = tid >> 3, c0 = (tid & 7) * 8;
    int r1 = (tid + 256) >> 3, c1 = (tid & 7) * 8;
    short8 rA0 = *(const short8*)(Wvb + (size_t)(m0g + r0) * 512 + c0);
    short8 rB0 = *(const short8*)(catb + (size_t)(n0g + r0) * 512 + c0);
    short8 rA1 = *(const short8*)(Wvb + (size_t)(m0g + r1) * 512 + c1);
    short8 rB1 = *(const short8*)(catb + (size_t)(n0g + r1) * 512 + c1);

#pragma unroll
    for (int t = 0; t < 8; ++t) {
        *(short8*)&Ald[r0][c0] = rA0; *(short8*)&Bld[r0][c0] = rB0;
        *(short8*)&Ald[r1][c1] = rA1; *(short8*)&Bld[r1][c1] = rB1;
        __syncthreads();
        if (t < 7) {
            int kn = (t + 1) * 64;
            rA0 = *(const short8*)(Wvb + (size_t)(m0g + r0) * 512 + kn + c0);
            rB0 = *(const short8*)(catb + (size_t)(n0g + r0) * 512 + kn + c0);
            rA1 = *(const short8*)(Wvb + (size_t)(m0g + r1) * 512 + kn + c1);
            rB1 = *(const short8*)(catb + (size_t)(n0g + r1) * 512 + kn + c1);
        }
#pragma unroll
        for (int ks = 0; ks < 2; ++ks) {
            short8 a[2], b[2];
#pragma unroll
            for (int i = 0; i < 2; ++i) a[i] = *(const short8*)&Ald[wm * 32 + i * 16 + l15][ks * 32 + lk];
#pragma unroll
            for (int j = 0; j < 2; ++j) b[j] = *(const short8*)&Bld[wn * 32 + j * 16 + l15][ks * 32 + lk];
#pragma unroll
            for (int i = 0; i < 2; ++i)
#pragma unroll
                for (int j = 0; j < 2; ++j) acc[i][j] = mfma16(a[i], b[j], acc[i][j]);
        }
        __syncthreads();
    }
#pragma unroll
    for (int i = 0; i < 2; ++i) {
        int ob = m0g + wm * 32 + i * 16 + (lane >> 4) * 4;
#pragma unroll
        for (int j = 0; j < 2; ++j) {
            int px = n0g + wn * 32 + j * 16 + l15;
            int b = px / HW, p = px - b * HW;
            f32x4 v = acc[i][j];
#pragma unroll
            for (int r = 0; r < 4; ++r) {
                out[((size_t)(b * 256 + ob + r)) * HW + p] = fmaxf(v[r] * sc_[i][r] + sh_[i][r], 0.f);
            }
        }
    }
}

extern "C" void kernel_launch(void* const* d_in, const int* in_sizes, int n_in,
                              void* d_out, int out_size, void* d_ws, size_t ws_size,
                              hipStream_t stream) {
    const float* x     = (const float*)d_in[0];
    const float* Wq    = (const float*)d_in[1];
    const float* Wk    = (const float*)d_in[2];
    const float* Wv    = (const float*)d_in[3];
    const float* bv    = (const float*)d_in[4];
    const float* gamma = (const float*)d_in[5];
    const float* beta  = (const float*)d_in[6];
    const float* rmean = (const float*)d_in[7];
    const float* rvar  = (const float*)d_in[8];
    float* out = (float*)d_out;

    float* Qall = (float*)d_ws;                              // [4*HW][64] f32
    float* Qn   = Qall + (size_t)4 * HW * 64;                // [2*HW][64] f32
    unsigned short* Kb = (unsigned short*)(Qn + (size_t)2 * HW * 64);  // [6*HW][64] bf16
    unsigned short* catb   = Kb + (size_t)6 * HW * 64;       // [4*HW][512]
    unsigned short* xlo    = catb + (size_t)4 * HW * 512;    // [4*HW][256]
    unsigned short* xt1lo  = xlo + (size_t)4 * HW * 256;     // [2*HW][256]
    unsigned short* Wqk_hi = xt1lo + (size_t)2 * HW * 256;   // [128][256]
    unsigned short* Wqk_lo = Wqk_hi + 128 * 256;
    unsigned short* Wvb    = Wqk_lo + 128 * 256;             // [256][512]

    prep<<<3648, 256, 0, stream>>>(x, Wq, Wk, Wv, catb, xlo, Wqk_hi, Wqk_lo, Wvb);

    // Q (f32) and K (bf16, rows 0..4HW) for all 4 batches
    projqk<<<dim3(392, 2), 256, 0, stream>>>(Wqk_hi, Wqk_lo, catb, 512, xlo, Qall, Kb);

    // align 1: ta = x[2:4], tb = x[0:2] -> xt1 (hi -> catb cols 256.., lo -> xt1lo)
    attn_kernel<<<784, 256, 0, stream>>>(Qall + (size_t)2 * HW * 64, Kb,
                                         /*selfOff=*/2 * HW, /*kbOff=*/0,
                                         catb, catb + 256, xt1lo);

    // Q,K of xt1 (K -> Kb rows 4HW..6HW)
    projqk<<<dim3(196, 2), 256, 0, stream>>>(Wqk_hi, Wqk_lo, catb + 256, 512, xt1lo,
                                             Qn, Kb + (size_t)4 * HW * 64);

    // align 2: ta = xt1, tb = x[2:4] -> xt2
    attn_kernel<<<784, 256, 0, stream>>>(Qn, Kb,
                                         /*selfOff=*/4 * HW, /*kbOff=*/2 * HW,
                                         catb + (size_t)2 * HW * 512,
                                         catb + (size_t)2 * HW * 512 + 256, nullptr);

    // fused 1x1 conv (512->256) + BN + ReLU
    conv_mfma<<<dim3(196, 4), 256, 0, stream>>>(catb, Wvb, bv, gamma, beta, rmean, rvar, out);
}